// Round 11
// baseline (38.227 us; speedup 1.0000x reference)
//
#include <hip/hip_runtime.h>
#include <math.h>

#define EPS 1e-8f

constexpr int B = 32, N = 1024, M = 128, H = 2;

constexpr int ROWS_A   = 32;            // rows of L per block
constexpr int CHUNKS_A = N / ROWS_A;    // 32 row-chunks
constexpr int NBLK_A   = B * CHUNKS_A * 2;  // 2048 blocks (col-split x2)
constexpr int ROWS_C   = 64;            // rows per k2 block
constexpr int CHUNKS_C = N / ROWS_C;    // 16

// ---- K1: per block (b, chunk, half): f/bpart over 32 L-rows x 512 cols,
// ----     AND e over 16 mem-rows. 2048 blocks, 20KB LDS -> 8 blocks/CU (100% occ).
// ----     R8: no min-waves clamp. R9: no register deferral. R10: LDS f-partials.
__global__ __launch_bounds__(256) void k1(const float* __restrict__ L,
                                          const float* __restrict__ Wold,
                                          const float* __restrict__ mem,
                                          const float* __restrict__ keys,
                                          const float* __restrict__ strengths,
                                          const int* __restrict__ head,
                                          float* __restrict__ fpart,
                                          float* __restrict__ bpart,
                                          float* __restrict__ e,
                                          float* __restrict__ outMC) {
    int bid   = blockIdx.x;
    int t     = threadIdx.x;
    int lane  = t & 63, wave = t >> 6;
    int b     = bid >> 6;          // bid / 64
    int rem   = bid & 63;
    int chunk = rem >> 1;
    int half  = rem & 1;
    int r0    = chunk * ROWS_A;
    int c0    = half * 512;

    if (bid < 16) outMC[bid * 256 + t] = 0.f;   // B*M = 4096 = 16*256

    __shared__ float sw[N];               // 4KB
    __shared__ float lds_b[4][512];       // 8KB
    __shared__ float lds_f[ROWS_A][64];   // 8KB

    reinterpret_cast<float4*>(sw)[t] =
        reinterpret_cast<const float4*>(Wold + (size_t)b * N)[t];
    __syncthreads();

    float4 wreg[2];
    float4 bacc[2];
#pragma unroll
    for (int s = 0; s < 2; ++s) {
        wreg[s] = reinterpret_cast<float4*>(sw)[c0 / 4 + lane + 64 * s];
        bacc[s] = make_float4(0.f, 0.f, 0.f, 0.f);
    }

    const float* Lb = L + (size_t)b * N * N;
    for (int r = wave; r < ROWS_A; r += 4) {          // 8 rows per wave
        int i = r0 + r;
        const float4* row = reinterpret_cast<const float4*>(Lb + (size_t)i * N + c0);
        float wi = sw[i];
        float pp = 0.f;
#pragma unroll
        for (int s = 0; s < 2; ++s) {
            float4 v = row[lane + 64 * s];
            pp += v.x * wreg[s].x + v.y * wreg[s].y + v.z * wreg[s].z + v.w * wreg[s].w;
            bacc[s].x += v.x * wi;
            bacc[s].y += v.y * wi;
            bacc[s].z += v.z * wi;
            bacc[s].w += v.w * wi;
        }
        lds_f[r][lane] = pp;      // single ds_write; no cross-lane dependency
    }

    // e-work: this block's 16 mem rows (halves split the 32-row chunk)
    {
        int l32 = lane & 31, hl = lane >> 5;
        int h   = head[0];
        float4 kv = reinterpret_cast<const float4*>(keys + ((size_t)b * H + h) * M)[l32];
        float  sk = kv.x * kv.x + kv.y * kv.y + kv.z * kv.z + kv.w * kv.w;
#pragma unroll
        for (int off = 16; off; off >>= 1) sk += __shfl_xor(sk, off, 64);
        float norm_k = sqrtf(sk);
        float beta   = strengths[(size_t)b * H + h];
#pragma unroll
        for (int rr = 0; rr < 2; ++rr) {              // 2 iters, 2 rows/wave/iter
            int n = r0 + half * 16 + wave * 4 + rr * 2 + hl;
            float4 mv = reinterpret_cast<const float4*>(mem + ((size_t)b * N + n) * M)[l32];
            float dot = mv.x * kv.x + mv.y * kv.y + mv.z * kv.z + mv.w * kv.w;
            float sm  = mv.x * mv.x + mv.y * mv.y + mv.z * mv.z + mv.w * mv.w;
#pragma unroll
            for (int off = 16; off; off >>= 1) {
                dot += __shfl_xor(dot, off, 64);
                sm  += __shfl_xor(sm, off, 64);
            }
            if (l32 == 0) {
                float denom = sqrtf(sm) * norm_k + EPS;
                e[(size_t)b * N + n] = expf(beta * dot / denom);
            }
        }
    }

#pragma unroll
    for (int s = 0; s < 2; ++s)
        reinterpret_cast<float4*>(lds_b[wave])[lane + 64 * s] = bacc[s];
    __syncthreads();

    // f block-reduce: 8 threads per row, each sums 8 lanes, then width-8 shfl.
    {
        int row = t >> 3, seg = t & 7;
        const float* src = &lds_f[row][seg * 8];
        float s = src[0] + src[1] + src[2] + src[3]
                + src[4] + src[5] + src[6] + src[7];
#pragma unroll
        for (int off = 4; off; off >>= 1) s += __shfl_down(s, off, 8);
        if (seg == 0) fpart[((size_t)b * 2 + half) * N + r0 + row] = s;
    }

    // bpart: this block's 512-col segment, 2 cols per thread
    {
        int c = 2 * t;
        float2 o;
        o.x = lds_b[0][c]     + lds_b[1][c]     + lds_b[2][c]     + lds_b[3][c];
        o.y = lds_b[0][c + 1] + lds_b[1][c + 1] + lds_b[2][c + 1] + lds_b[3][c + 1];
        reinterpret_cast<float2*>(bpart + ((size_t)b * CHUNKS_A + chunk) * N + c0)[t] = o;
    }
}

// ---- K2: per 64-row chunk. Redundant S = sum(e[b][:]) (4KB, cache-hot),
// ----     bsum from bpart, W written directly to outW, and the chunk's
// ----     mc partial accumulated into outMC via atomicAdd (16 adds/address).
__global__ __launch_bounds__(256) void k2(const float* __restrict__ mem,
                                          const float* __restrict__ bpart,
                                          const float* __restrict__ fpart,
                                          const float* __restrict__ e,
                                          const float* __restrict__ mode,
                                          const int* __restrict__ head,
                                          float* __restrict__ outW,
                                          float* __restrict__ outMC) {
    int bid   = blockIdx.x;
    int b     = bid / CHUNKS_C;
    int chunk = bid % CHUNKS_C;
    int t     = threadIdx.x;
    int lane  = t & 63, wave = t >> 6;
    int r0    = chunk * ROWS_C;

    __shared__ float sred[4];
    __shared__ float bp[4][ROWS_C];
    __shared__ float swv[ROWS_C];
    __shared__ float4 lW[8][32];

    // phase 0: S = sum over e[b][:]
    float4 ev4 = reinterpret_cast<const float4*>(e + (size_t)b * N)[t];
    float es = ev4.x + ev4.y + ev4.z + ev4.w;
#pragma unroll
    for (int off = 32; off; off >>= 1) es += __shfl_down(es, off, 64);
    if (lane == 0) sred[wave] = es;

    // phase 1: bsum partials over CHUNKS_A, split across 4 c-groups
    int n_ = t & 63, cg_ = t >> 6;
    float s = 0.f;
#pragma unroll
    for (int c = cg_; c < CHUNKS_A; c += 4)
        s += bpart[((size_t)b * CHUNKS_A + c) * N + r0 + n_];
    __syncthreads();
    bp[cg_][n_] = s;
    __syncthreads();

    float S = sred[0] + sred[1] + sred[2] + sred[3];
    int h = head[0];
    const float* rm = mode + ((size_t)b * H + h) * 3;
    float coef = rm[1] / S;
    if (t < ROWS_C) {
        float bsum = bp[0][t] + bp[1][t] + bp[2][t] + bp[3][t];
        float fv = fpart[((size_t)b * 2 + 0) * N + r0 + t]
                 + fpart[((size_t)b * 2 + 1) * N + r0 + t];
        float w = rm[0] * bsum + coef * e[(size_t)b * N + r0 + t] + rm[2] * fv;
        swv[t] = w;
        outW[(size_t)b * N + r0 + t] = w;
    }
    __syncthreads();

    // phase 2: fused mc partial over this chunk's 64 rows
    int cg = t & 31, rg = t >> 5;
    float4 aW = make_float4(0.f, 0.f, 0.f, 0.f);
#pragma unroll
    for (int rr = 0; rr < ROWS_C / 8; ++rr) {
        int r = rg + rr * 8;
        float4 v = reinterpret_cast<const float4*>(mem + ((size_t)b * N + r0 + r) * M)[cg];
        float ww = swv[r];
        aW.x += ww * v.x; aW.y += ww * v.y; aW.z += ww * v.z; aW.w += ww * v.w;
    }
    lW[rg][cg] = aW;
    __syncthreads();

    if (t < 32) {
        float4 oW = make_float4(0.f, 0.f, 0.f, 0.f);
#pragma unroll
        for (int g = 0; g < 8; ++g) {
            float4 vW = lW[g][t];
            oW.x += vW.x; oW.y += vW.y; oW.z += vW.z; oW.w += vW.w;
        }
        float* dst = outMC + (size_t)b * M + 4 * t;
        atomicAdd(dst + 0, oW.x);
        atomicAdd(dst + 1, oW.y);
        atomicAdd(dst + 2, oW.z);
        atomicAdd(dst + 3, oW.w);
    }
}

extern "C" void kernel_launch(void* const* d_in, const int* in_sizes, int n_in,
                              void* d_out, int out_size, void* d_ws, size_t ws_size,
                              hipStream_t stream) {
    const float* read_keys      = (const float*)d_in[0];
    const float* read_strengths = (const float*)d_in[1];
    const float* read_mode      = (const float*)d_in[2];
    const float* W_old          = (const float*)d_in[3];
    const float* L              = (const float*)d_in[4];
    const float* memory         = (const float*)d_in[5];
    const int*   head_no        = (const int*)d_in[6];

    float* out_W  = (float*)d_out;             // B*N
    float* out_mc = out_W + (size_t)B * N;     // B*M

    float* ws    = (float*)d_ws;
    float* fpart = ws;                                    // B*2*N
    float* bpart = fpart + (size_t)B * 2 * N;             // B*CHUNKS_A*N (4 MB)
    float* e     = bpart + (size_t)B * CHUNKS_A * N;      // B*N

    k1<<<NBLK_A, 256, 0, stream>>>(L, W_old, memory, read_keys,
                                   read_strengths, head_no, fpart, bpart, e, out_mc);
    k2<<<B * CHUNKS_C, 256, 0, stream>>>(memory, bpart, fpart, e, read_mode, head_no,
                                         out_W, out_mc);
}